// Round 7
// baseline (704.479 us; speedup 1.0000x reference)
//
#include <hip/hip_runtime.h>

#define EE 512
#define HH 256
#define QQ 1024
#define SS 512
#define NSTEPS 3
#define NBLK 512

// ---------------------------------------------------------------------------
// Grid barrier: slot-per-use counters in global ws (memset to 0 each launch).
// Release: threadfence + atomicAdd; acquire: spin + threadfence. All blocks
// call every barrier in the same order (no divergent skips).
// ---------------------------------------------------------------------------
__device__ __forceinline__ void gbar(int* __restrict__ bar, int slot) {
    __syncthreads();
    if (threadIdx.x == 0) {
        __threadfence();
        atomicAdd(&bar[slot], 1);
        while (__hip_atomic_load(&bar[slot], __ATOMIC_RELAXED,
                                 __HIP_MEMORY_SCOPE_AGENT) < NBLK)
            __builtin_amdgcn_s_sleep(4);
        __threadfence();
    }
    __syncthreads();
}

// ---------------------------------------------------------------------------
// Round-5 32x64 GEMM tile (proven): 256 thr, BK=32, reg-prefetch dbuf,
// X-tile k-major. N fixed = 256. acc rows m0+ty2{+0,1}, cols n0+4*tx..+3.
// ---------------------------------------------------------------------------
__device__ __forceinline__ void mm_tile(const float* __restrict__ Xrow, int K,
                                        const float* __restrict__ Wcol,
                                        float (*Xs)[66], float (*Ws)[68],
                                        float acc[2][4]) {
    const int tid = threadIdx.x;
    const int r   = tid >> 3;
    const int c4  = (tid & 7) << 2;
    const int c8  = (tid & 7) << 3;
    const int tx  = tid & 15;
    const int ty2 = (tid >> 4) << 1;

    float4 vx  = *(const float4*)&Xrow[r * K + c4];
    float4 vw0 = *(const float4*)&Wcol[r * HH + c8];
    float4 vw1 = *(const float4*)&Wcol[r * HH + c8 + 4];

    for (int k0 = 0; k0 < K; k0 += 32) {
        Xs[c4 + 0][r] = vx.x;
        Xs[c4 + 1][r] = vx.y;
        Xs[c4 + 2][r] = vx.z;
        Xs[c4 + 3][r] = vx.w;
        *(float4*)&Ws[r][c8]     = vw0;
        *(float4*)&Ws[r][c8 + 4] = vw1;
        __syncthreads();
        if (k0 + 32 < K) {
            vx  = *(const float4*)&Xrow[r * K + k0 + 32 + c4];
            vw0 = *(const float4*)&Wcol[(k0 + 32 + r) * HH + c8];
            vw1 = *(const float4*)&Wcol[(k0 + 32 + r) * HH + c8 + 4];
        }
        #pragma unroll
        for (int kk = 0; kk < 32; kk++) {
            float4 w = *(const float4*)&Ws[kk][tx << 2];
            float2 a = *(const float2*)&Xs[kk][ty2];
            acc[0][0] += a.x * w.x; acc[0][1] += a.x * w.y;
            acc[0][2] += a.x * w.z; acc[0][3] += a.x * w.w;
            acc[1][0] += a.y * w.x; acc[1][1] += a.y * w.y;
            acc[1][2] += a.y * w.z; acc[1][3] += a.y * w.w;
        }
        __syncthreads();
    }
}

// ---------------------------------------------------------------------------
// Persistent fused kernel: 12 grid barriers, phases are round-5 kernel bodies.
// LDS: one 17152 B arena, re-cast per phase (barriers bracket all reuse).
// ---------------------------------------------------------------------------
__global__ __launch_bounds__(256, 2) void fused_k(
    const float* __restrict__ qf,  const float* __restrict__ sf,
    const int*   __restrict__ y,
    const float* __restrict__ Wn1, const float* __restrict__ bn1,
    const float* __restrict__ Wn2, const float* __restrict__ bn2,
    const float* __restrict__ Wm1, const float* __restrict__ bm1,
    const float* __restrict__ Wm2, const float* __restrict__ bm2,
    const float* __restrict__ Wr1, const float* __restrict__ br1,
    const float* __restrict__ wr2, const float* __restrict__ br2,
    float* __restrict__ out, float* __restrict__ ws, int* __restrict__ bar) {

    __shared__ char smem[17152];
    float (*Xs)[66] = (float(*)[66])smem;
    float (*Ws)[68] = (float(*)[68])(smem + 8448);

    float* X1   = ws;                 // 1536*256
    float* QS   = ws + 393216;        // 1536*256
    float* q    = QS;
    float* s    = QS + QQ * HH;
    float* Am   = ws + 786432;        // 512*256
    float* Bm   = ws + 917504;        // 512*256
    float* hsum = ws + 1048576;       // 512*256
    float* hq   = ws + 1179648;       // 1024*256
    float* hsT  = ws + 1441792;       // 256*512
    float* cntf = ws + 1572864;       // 512
    float* invd = ws + 1573376;       // 512
    int* cls_cnt  = (int*)(ws + 1573888);   // 16
    int* cls_list = (int*)(ws + 1573904);   // 16*512

    const int b   = blockIdx.x;
    const int tid = threadIdx.x;
    const int tx  = tid & 15;
    const int ty2 = (tid >> 4) << 1;
    int slot = 0;

    // ---- P0: E1 (192 jobs) + class stats (job 192) ----
    if (b < 192) {
        int m0 = (b >> 2) << 5, n0 = (b & 3) << 6;
        const float* src = (m0 < QQ) ? (qf + m0 * EE) : (sf + (m0 - QQ) * EE);
        float acc[2][4] = {{0,0,0,0},{0,0,0,0}};
        mm_tile(src, EE, Wn1 + n0, Xs, Ws, acc);
        #pragma unroll
        for (int rr = 0; rr < 2; rr++) {
            int m = m0 + ty2 + rr, n = n0 + (tx << 2);
            float4 o;
            o.x = fmaxf(acc[rr][0] + bn1[n + 0], 0.f);
            o.y = fmaxf(acc[rr][1] + bn1[n + 1], 0.f);
            o.z = fmaxf(acc[rr][2] + bn1[n + 2], 0.f);
            o.w = fmaxf(acc[rr][3] + bn1[n + 3], 0.f);
            *(float4*)&X1[m * HH + n] = o;
        }
    } else if (b == 192) {
        int* lc = (int*)smem;
        if (tid < 16) lc[tid] = 0;
        __syncthreads();
        for (int i = tid; i < SS; i += 256) {
            int c = y[i];
            int pos = atomicAdd(&lc[c], 1);
            cls_list[c * SS + pos] = i;
        }
        __syncthreads();
        if (tid < 16) cls_cnt[tid] = lc[tid];
        for (int i = tid; i < SS; i += 256) {
            float n = (float)(lc[y[i]] - 1);
            cntf[i] = n;
            invd[i] = 1.f / fmaxf(n, 1.f);
        }
    }
    gbar(bar, slot++);

    // ---- P1: E2 (192 jobs): QS = X1 @ Wn2 + bn2 ----
    if (b < 192) {
        int m0 = (b >> 2) << 5, n0 = (b & 3) << 6;
        float acc[2][4] = {{0,0,0,0},{0,0,0,0}};
        mm_tile(X1 + m0 * HH, HH, Wn2 + n0, Xs, Ws, acc);
        #pragma unroll
        for (int rr = 0; rr < 2; rr++) {
            int m = m0 + ty2 + rr, n = n0 + (tx << 2);
            float4 o;
            o.x = acc[rr][0] + bn2[n + 0]; o.y = acc[rr][1] + bn2[n + 1];
            o.z = acc[rr][2] + bn2[n + 2]; o.w = acc[rr][3] + bn2[n + 3];
            *(float4*)&QS[m * HH + n] = o;
        }
    }
    gbar(bar, slot++);

    // ---- message-passing steps ----
    for (int t = 0; t < NSTEPS; t++) {
        const float* W1t = Wm1 + t * 2 * HH * HH;
        const float* b1t = bm1 + t * HH;
        const float* W2t = Wm2 + t * HH * HH;
        const float* b2t = bm2 + t * HH;

        // PA: A = s@W1a, B = s@W1b (128 jobs); t==0 also hq = q@Wr1a (128)
        if (b < 128) {
            int which = b >> 6, jj = b & 63;
            int m0 = (jj >> 2) << 5, n0 = (jj & 3) << 6;
            const float* W = W1t + which * HH * HH;
            float* C = which ? Bm : Am;
            float acc[2][4] = {{0,0,0,0},{0,0,0,0}};
            mm_tile(s + m0 * HH, HH, W + n0, Xs, Ws, acc);
            #pragma unroll
            for (int rr = 0; rr < 2; rr++) {
                int m = m0 + ty2 + rr, n = n0 + (tx << 2);
                float4 o = { acc[rr][0], acc[rr][1], acc[rr][2], acc[rr][3] };
                *(float4*)&C[m * HH + n] = o;
            }
        } else if (t == 0 && b < 256) {
            int jj = b - 128;
            int m0 = (jj >> 2) << 5, n0 = (jj & 3) << 6;
            float acc[2][4] = {{0,0,0,0},{0,0,0,0}};
            mm_tile(q + m0 * HH, HH, Wr1 + n0, Xs, Ws, acc);
            #pragma unroll
            for (int rr = 0; rr < 2; rr++) {
                int m = m0 + ty2 + rr, n = n0 + (tx << 2);
                float4 o = { acc[rr][0], acc[rr][1], acc[rr][2], acc[rr][3] };
                *(float4*)&hq[m * HH + n] = o;
            }
        }
        gbar(bar, slot++);

        // PH: hsum (512 jobs, job i = b)
        {
            int* lst = (int*)smem;
            const int i = b;
            int yi = y[i];
            int cnt = cls_cnt[yi];
            const int* Lp = cls_list + yi * SS;
            for (int m = tid; m < cnt; m += 256) lst[m] = Lp[m];
            __syncthreads();
            float a = Am[i * HH + tid] + b1t[tid];
            float acc = 0.f;
            int m = 0;
            for (; m + 4 <= cnt; m += 4) {
                float v0 = Bm[lst[m + 0] * HH + tid];
                float v1 = Bm[lst[m + 1] * HH + tid];
                float v2 = Bm[lst[m + 2] * HH + tid];
                float v3 = Bm[lst[m + 3] * HH + tid];
                acc += fmaxf(a + v0, 0.f) + fmaxf(a + v1, 0.f)
                     + fmaxf(a + v2, 0.f) + fmaxf(a + v3, 0.f);
            }
            for (; m < cnt; m++) acc += fmaxf(a + Bm[lst[m] * HH + tid], 0.f);
            acc -= fmaxf(a + Bm[i * HH + tid], 0.f);   // remove self
            hsum[i * HH + tid] = acc;
        }
        gbar(bar, slot++);

        // PG: s += (hsum@W2 + cnt*bm2) * invd (64 jobs)
        if (b < 64) {
            int m0 = (b >> 2) << 5, n0 = (b & 3) << 6;
            float acc[2][4] = {{0,0,0,0},{0,0,0,0}};
            mm_tile(hsum + m0 * HH, HH, W2t + n0, Xs, Ws, acc);
            #pragma unroll
            for (int rr = 0; rr < 2; rr++) {
                int m = m0 + ty2 + rr, n = n0 + (tx << 2);
                float ci = cntf[m], di = invd[m];
                float* sp = &s[m * HH + n];
                float4 sv = *(float4*)sp;
                float4 o;
                o.x = sv.x + (acc[rr][0] + ci * b2t[n + 0]) * di;
                o.y = sv.y + (acc[rr][1] + ci * b2t[n + 1]) * di;
                o.z = sv.z + (acc[rr][2] + ci * b2t[n + 2]) * di;
                o.w = sv.w + (acc[rr][3] + ci * b2t[n + 3]) * di;
                *(float4*)sp = o;
            }
        }
        gbar(bar, slot++);
    }

    // ---- PT: hsT[h][j] = (s@Wr1b)[j][h] + br1[h]  (64 jobs) ----
    if (b < 64) {
        int m0 = (b >> 2) << 5, n0 = (b & 3) << 6;
        float acc[2][4] = {{0,0,0,0},{0,0,0,0}};
        mm_tile(s + m0 * HH, HH, Wr1 + HH * HH + n0, Xs, Ws, acc);
        #pragma unroll
        for (int rr = 0; rr < 2; rr++) {
            int m = m0 + ty2 + rr;
            #pragma unroll
            for (int cc = 0; cc < 4; cc++) {
                int n = n0 + (tx << 2) + cc;
                hsT[n * SS + m] = acc[rr][cc] + br1[n];
            }
        }
    }
    gbar(bar, slot++);

    // ---- PS: scores (512 jobs): 4 i-rows x 256 j per job ----
    {
        float (*hqs)[HH] = (float(*)[HH])smem;
        float* w2s = (float*)(smem + 4096);
        const int i0 = (b >> 1) << 2;
        const int j  = ((b & 1) << 8) + tid;
        w2s[tid] = wr2[tid];
        #pragma unroll
        for (int ii = 0; ii < 4; ii++) hqs[ii][tid] = hq[(i0 + ii) * HH + tid];
        __syncthreads();
        float acc[4] = {0, 0, 0, 0};
        for (int h0 = 0; h0 < HH; h0 += 8) {
            float v[8];
            #pragma unroll
            for (int u = 0; u < 8; u++) v[u] = hsT[(h0 + u) * SS + j];
            float4 w0 = *(const float4*)&w2s[h0];
            float4 w1 = *(const float4*)&w2s[h0 + 4];
            #pragma unroll
            for (int ii = 0; ii < 4; ii++) {
                float4 a0 = *(const float4*)&hqs[ii][h0];
                float4 a1 = *(const float4*)&hqs[ii][h0 + 4];
                acc[ii] += fmaxf(v[0] + a0.x, 0.f) * w0.x
                         + fmaxf(v[1] + a0.y, 0.f) * w0.y
                         + fmaxf(v[2] + a0.z, 0.f) * w0.z
                         + fmaxf(v[3] + a0.w, 0.f) * w0.w
                         + fmaxf(v[4] + a1.x, 0.f) * w1.x
                         + fmaxf(v[5] + a1.y, 0.f) * w1.y
                         + fmaxf(v[6] + a1.z, 0.f) * w1.z
                         + fmaxf(v[7] + a1.w, 0.f) * w1.w;
            }
        }
        float b2 = br2[0];
        #pragma unroll
        for (int ii = 0; ii < 4; ii++)
            out[(i0 + ii) * SS + j] = acc[ii] + b2;
    }
}

extern "C" void kernel_launch(void* const* d_in, const int* in_sizes, int n_in,
                              void* d_out, int out_size, void* d_ws, size_t ws_size,
                              hipStream_t stream) {
    const float* qf  = (const float*)d_in[0];
    const float* sf  = (const float*)d_in[1];
    const int*   y   = (const int*)d_in[2];
    const float* Wn1 = (const float*)d_in[3];
    const float* bn1 = (const float*)d_in[4];
    const float* Wn2 = (const float*)d_in[5];
    const float* bn2 = (const float*)d_in[6];
    const float* Wm1 = (const float*)d_in[7];
    const float* bm1 = (const float*)d_in[8];
    const float* Wm2 = (const float*)d_in[9];
    const float* bm2 = (const float*)d_in[10];
    const float* Wr1 = (const float*)d_in[11];
    const float* br1 = (const float*)d_in[12];
    const float* wr2 = (const float*)d_in[13];
    const float* br2 = (const float*)d_in[14];
    float* out = (float*)d_out;
    float* ws  = (float*)d_ws;
    int*   bar = (int*)(ws + 1582336);   // 16 barrier slots, past all buffers

    hipMemsetAsync(bar, 0, 16 * sizeof(int), stream);
    fused_k<<<NBLK, 256, 0, stream>>>(qf, sf, y, Wn1, bn1, Wn2, bn2,
                                      Wm1, bm1, Wm2, bm2, Wr1, br1, wr2, br2,
                                      out, ws, bar);
}

// Round 8
// 341.809 us; speedup vs baseline: 2.0610x; 2.0610x over previous
//
#include <hip/hip_runtime.h>

#define EE 512
#define HH 256
#define QQ 1024
#define SS 512
#define NSTEPS 3
#define NBLK 256

// ---------------------------------------------------------------------------
// Grid barrier v2 (low contention):
//  - arrival counter and release flag on SEPARATE 256B-spaced lines
//  - only block 0 polls the counter; others poll the release flag w/ backoff
//  - slots memset to 0 by hipMemsetAsync each launch (capture-safe)
// ---------------------------------------------------------------------------
__device__ __forceinline__ void gbar(int* __restrict__ bar, int slot) {
    __syncthreads();
    if (threadIdx.x == 0) {
        int* cnt = &bar[slot * 64];
        int* rel = &bar[slot * 64 + 32];
        __threadfence();
        atomicAdd(cnt, 1);
        if (blockIdx.x == 0) {
            while (__hip_atomic_load(cnt, __ATOMIC_RELAXED,
                                     __HIP_MEMORY_SCOPE_AGENT) < NBLK)
                __builtin_amdgcn_s_sleep(1);
            __hip_atomic_store(rel, 1, __ATOMIC_RELEASE,
                               __HIP_MEMORY_SCOPE_AGENT);
        } else {
            while (__hip_atomic_load(rel, __ATOMIC_RELAXED,
                                     __HIP_MEMORY_SCOPE_AGENT) == 0)
                __builtin_amdgcn_s_sleep(16);
        }
        __threadfence();
    }
    __syncthreads();
}

// ---------------------------------------------------------------------------
// Round-5 32x64 GEMM tile (proven): 256 thr, BK=32, reg-prefetch dbuf,
// X-tile k-major. N fixed = 256. acc rows m0+ty2{+0,1}, cols n0+4*tx..+3.
// ---------------------------------------------------------------------------
__device__ __forceinline__ void mm_tile(const float* __restrict__ Xrow, int K,
                                        const float* __restrict__ Wcol,
                                        float (*Xs)[66], float (*Ws)[68],
                                        float acc[2][4]) {
    const int tid = threadIdx.x;
    const int r   = tid >> 3;
    const int c4  = (tid & 7) << 2;
    const int c8  = (tid & 7) << 3;
    const int tx  = tid & 15;
    const int ty2 = (tid >> 4) << 1;

    float4 vx  = *(const float4*)&Xrow[r * K + c4];
    float4 vw0 = *(const float4*)&Wcol[r * HH + c8];
    float4 vw1 = *(const float4*)&Wcol[r * HH + c8 + 4];

    for (int k0 = 0; k0 < K; k0 += 32) {
        Xs[c4 + 0][r] = vx.x;
        Xs[c4 + 1][r] = vx.y;
        Xs[c4 + 2][r] = vx.z;
        Xs[c4 + 3][r] = vx.w;
        *(float4*)&Ws[r][c8]     = vw0;
        *(float4*)&Ws[r][c8 + 4] = vw1;
        __syncthreads();
        if (k0 + 32 < K) {
            vx  = *(const float4*)&Xrow[r * K + k0 + 32 + c4];
            vw0 = *(const float4*)&Wcol[(k0 + 32 + r) * HH + c8];
            vw1 = *(const float4*)&Wcol[(k0 + 32 + r) * HH + c8 + 4];
        }
        #pragma unroll
        for (int kk = 0; kk < 32; kk++) {
            float4 w = *(const float4*)&Ws[kk][tx << 2];
            float2 a = *(const float2*)&Xs[kk][ty2];
            acc[0][0] += a.x * w.x; acc[0][1] += a.x * w.y;
            acc[0][2] += a.x * w.z; acc[0][3] += a.x * w.w;
            acc[1][0] += a.y * w.x; acc[1][1] += a.y * w.y;
            acc[1][2] += a.y * w.z; acc[1][3] += a.y * w.w;
        }
        __syncthreads();
    }
}

// ---------------------------------------------------------------------------
// Persistent fused kernel, NBLK=256: 12 low-contention grid barriers.
// 512-job phases (hsum, scores) loop 2 jobs per block.
// ---------------------------------------------------------------------------
__global__ __launch_bounds__(256, 2) void fused_k(
    const float* __restrict__ qf,  const float* __restrict__ sf,
    const int*   __restrict__ y,
    const float* __restrict__ Wn1, const float* __restrict__ bn1,
    const float* __restrict__ Wn2, const float* __restrict__ bn2,
    const float* __restrict__ Wm1, const float* __restrict__ bm1,
    const float* __restrict__ Wm2, const float* __restrict__ bm2,
    const float* __restrict__ Wr1, const float* __restrict__ br1,
    const float* __restrict__ wr2, const float* __restrict__ br2,
    float* __restrict__ out, float* __restrict__ ws, int* __restrict__ bar) {

    __shared__ char smem[17152];
    float (*Xs)[66] = (float(*)[66])smem;
    float (*Ws)[68] = (float(*)[68])(smem + 8448);

    float* X1   = ws;                 // 1536*256
    float* QS   = ws + 393216;        // 1536*256
    float* q    = QS;
    float* s    = QS + QQ * HH;
    float* Am   = ws + 786432;        // 512*256
    float* Bm   = ws + 917504;        // 512*256
    float* hsum = ws + 1048576;       // 512*256
    float* hq   = ws + 1179648;       // 1024*256
    float* hsT  = ws + 1441792;       // 256*512
    float* cntf = ws + 1572864;       // 512
    float* invd = ws + 1573376;       // 512
    int* cls_cnt  = (int*)(ws + 1573888);   // 16
    int* cls_list = (int*)(ws + 1573904);   // 16*512

    const int b   = blockIdx.x;
    const int tid = threadIdx.x;
    const int tx  = tid & 15;
    const int ty2 = (tid >> 4) << 1;
    int slot = 0;

    // ---- P0: E1 (192 jobs) + class stats (job 192) ----
    if (b < 192) {
        int m0 = (b >> 2) << 5, n0 = (b & 3) << 6;
        const float* src = (m0 < QQ) ? (qf + m0 * EE) : (sf + (m0 - QQ) * EE);
        float acc[2][4] = {{0,0,0,0},{0,0,0,0}};
        mm_tile(src, EE, Wn1 + n0, Xs, Ws, acc);
        #pragma unroll
        for (int rr = 0; rr < 2; rr++) {
            int m = m0 + ty2 + rr, n = n0 + (tx << 2);
            float4 o;
            o.x = fmaxf(acc[rr][0] + bn1[n + 0], 0.f);
            o.y = fmaxf(acc[rr][1] + bn1[n + 1], 0.f);
            o.z = fmaxf(acc[rr][2] + bn1[n + 2], 0.f);
            o.w = fmaxf(acc[rr][3] + bn1[n + 3], 0.f);
            *(float4*)&X1[m * HH + n] = o;
        }
    } else if (b == 192) {
        int* lc = (int*)smem;
        if (tid < 16) lc[tid] = 0;
        __syncthreads();
        for (int i = tid; i < SS; i += 256) {
            int c = y[i];
            int pos = atomicAdd(&lc[c], 1);
            cls_list[c * SS + pos] = i;
        }
        __syncthreads();
        if (tid < 16) cls_cnt[tid] = lc[tid];
        for (int i = tid; i < SS; i += 256) {
            float n = (float)(lc[y[i]] - 1);
            cntf[i] = n;
            invd[i] = 1.f / fmaxf(n, 1.f);
        }
    }
    gbar(bar, slot++);

    // ---- P1: E2 (192 jobs): QS = X1 @ Wn2 + bn2 ----
    if (b < 192) {
        int m0 = (b >> 2) << 5, n0 = (b & 3) << 6;
        float acc[2][4] = {{0,0,0,0},{0,0,0,0}};
        mm_tile(X1 + m0 * HH, HH, Wn2 + n0, Xs, Ws, acc);
        #pragma unroll
        for (int rr = 0; rr < 2; rr++) {
            int m = m0 + ty2 + rr, n = n0 + (tx << 2);
            float4 o;
            o.x = acc[rr][0] + bn2[n + 0]; o.y = acc[rr][1] + bn2[n + 1];
            o.z = acc[rr][2] + bn2[n + 2]; o.w = acc[rr][3] + bn2[n + 3];
            *(float4*)&QS[m * HH + n] = o;
        }
    }
    gbar(bar, slot++);

    // ---- message-passing steps ----
    for (int t = 0; t < NSTEPS; t++) {
        const float* W1t = Wm1 + t * 2 * HH * HH;
        const float* b1t = bm1 + t * HH;
        const float* W2t = Wm2 + t * HH * HH;
        const float* b2t = bm2 + t * HH;

        // PA: A = s@W1a, B = s@W1b (128 jobs); t==0: blocks 128..255 do hq
        if (b < 128) {
            int which = b >> 6, jj = b & 63;
            int m0 = (jj >> 2) << 5, n0 = (jj & 3) << 6;
            const float* W = W1t + which * HH * HH;
            float* C = which ? Bm : Am;
            float acc[2][4] = {{0,0,0,0},{0,0,0,0}};
            mm_tile(s + m0 * HH, HH, W + n0, Xs, Ws, acc);
            #pragma unroll
            for (int rr = 0; rr < 2; rr++) {
                int m = m0 + ty2 + rr, n = n0 + (tx << 2);
                float4 o = { acc[rr][0], acc[rr][1], acc[rr][2], acc[rr][3] };
                *(float4*)&C[m * HH + n] = o;
            }
        } else if (t == 0) {
            int jj = b - 128;           // 128 hq jobs
            int m0 = (jj >> 2) << 5, n0 = (jj & 3) << 6;
            float acc[2][4] = {{0,0,0,0},{0,0,0,0}};
            mm_tile(q + m0 * HH, HH, Wr1 + n0, Xs, Ws, acc);
            #pragma unroll
            for (int rr = 0; rr < 2; rr++) {
                int m = m0 + ty2 + rr, n = n0 + (tx << 2);
                float4 o = { acc[rr][0], acc[rr][1], acc[rr][2], acc[rr][3] };
                *(float4*)&hq[m * HH + n] = o;
            }
        }
        gbar(bar, slot++);

        // PH: hsum (512 jobs: i = b and b+256)
        {
            int* lst = (int*)smem;
            for (int jj = 0; jj < 2; jj++) {
                const int i = b + (jj << 8);
                int yi = y[i];
                int cnt = cls_cnt[yi];
                const int* Lp = cls_list + yi * SS;
                __syncthreads();                       // guard smem reuse
                for (int m = tid; m < cnt; m += 256) lst[m] = Lp[m];
                __syncthreads();
                float a = Am[i * HH + tid] + b1t[tid];
                float acc = 0.f;
                int m = 0;
                for (; m + 4 <= cnt; m += 4) {
                    float v0 = Bm[lst[m + 0] * HH + tid];
                    float v1 = Bm[lst[m + 1] * HH + tid];
                    float v2 = Bm[lst[m + 2] * HH + tid];
                    float v3 = Bm[lst[m + 3] * HH + tid];
                    acc += fmaxf(a + v0, 0.f) + fmaxf(a + v1, 0.f)
                         + fmaxf(a + v2, 0.f) + fmaxf(a + v3, 0.f);
                }
                for (; m < cnt; m++) acc += fmaxf(a + Bm[lst[m] * HH + tid], 0.f);
                acc -= fmaxf(a + Bm[i * HH + tid], 0.f);   // remove self
                hsum[i * HH + tid] = acc;
            }
        }
        gbar(bar, slot++);

        // PG: s += (hsum@W2 + cnt*bm2) * invd (64 jobs)
        if (b < 64) {
            int m0 = (b >> 2) << 5, n0 = (b & 3) << 6;
            float acc[2][4] = {{0,0,0,0},{0,0,0,0}};
            mm_tile(hsum + m0 * HH, HH, W2t + n0, Xs, Ws, acc);
            #pragma unroll
            for (int rr = 0; rr < 2; rr++) {
                int m = m0 + ty2 + rr, n = n0 + (tx << 2);
                float ci = cntf[m], di = invd[m];
                float* sp = &s[m * HH + n];
                float4 sv = *(float4*)sp;
                float4 o;
                o.x = sv.x + (acc[rr][0] + ci * b2t[n + 0]) * di;
                o.y = sv.y + (acc[rr][1] + ci * b2t[n + 1]) * di;
                o.z = sv.z + (acc[rr][2] + ci * b2t[n + 2]) * di;
                o.w = sv.w + (acc[rr][3] + ci * b2t[n + 3]) * di;
                *(float4*)sp = o;
            }
        }
        gbar(bar, slot++);
    }

    // ---- PT: hsT[h][j] = (s@Wr1b)[j][h] + br1[h]  (64 jobs) ----
    if (b < 64) {
        int m0 = (b >> 2) << 5, n0 = (b & 3) << 6;
        float acc[2][4] = {{0,0,0,0},{0,0,0,0}};
        mm_tile(s + m0 * HH, HH, Wr1 + HH * HH + n0, Xs, Ws, acc);
        #pragma unroll
        for (int rr = 0; rr < 2; rr++) {
            int m = m0 + ty2 + rr;
            #pragma unroll
            for (int cc = 0; cc < 4; cc++) {
                int n = n0 + (tx << 2) + cc;
                hsT[n * SS + m] = acc[rr][cc] + br1[n];
            }
        }
    }
    gbar(bar, slot++);

    // ---- PS: scores (512 jobs: job = b and b+256) ----
    {
        float (*hqs)[HH] = (float(*)[HH])smem;
        float* w2s = (float*)(smem + 4096);
        const float b2 = br2[0];
        for (int jj = 0; jj < 2; jj++) {
            const int job = b + (jj << 8);
            const int i0 = (job >> 1) << 2;
            const int j  = ((job & 1) << 8) + tid;
            __syncthreads();                          // guard smem reuse
            w2s[tid] = wr2[tid];
            #pragma unroll
            for (int ii = 0; ii < 4; ii++) hqs[ii][tid] = hq[(i0 + ii) * HH + tid];
            __syncthreads();
            float acc[4] = {0, 0, 0, 0};
            for (int h0 = 0; h0 < HH; h0 += 8) {
                float v[8];
                #pragma unroll
                for (int u = 0; u < 8; u++) v[u] = hsT[(h0 + u) * SS + j];
                float4 w0 = *(const float4*)&w2s[h0];
                float4 w1 = *(const float4*)&w2s[h0 + 4];
                #pragma unroll
                for (int ii = 0; ii < 4; ii++) {
                    float4 a0 = *(const float4*)&hqs[ii][h0];
                    float4 a1 = *(const float4*)&hqs[ii][h0 + 4];
                    acc[ii] += fmaxf(v[0] + a0.x, 0.f) * w0.x
                             + fmaxf(v[1] + a0.y, 0.f) * w0.y
                             + fmaxf(v[2] + a0.z, 0.f) * w0.z
                             + fmaxf(v[3] + a0.w, 0.f) * w0.w
                             + fmaxf(v[4] + a1.x, 0.f) * w1.x
                             + fmaxf(v[5] + a1.y, 0.f) * w1.y
                             + fmaxf(v[6] + a1.z, 0.f) * w1.z
                             + fmaxf(v[7] + a1.w, 0.f) * w1.w;
                }
            }
            #pragma unroll
            for (int ii = 0; ii < 4; ii++)
                out[(i0 + ii) * SS + j] = acc[ii] + b2;
        }
    }
}

extern "C" void kernel_launch(void* const* d_in, const int* in_sizes, int n_in,
                              void* d_out, int out_size, void* d_ws, size_t ws_size,
                              hipStream_t stream) {
    const float* qf  = (const float*)d_in[0];
    const float* sf  = (const float*)d_in[1];
    const int*   y   = (const int*)d_in[2];
    const float* Wn1 = (const float*)d_in[3];
    const float* bn1 = (const float*)d_in[4];
    const float* Wn2 = (const float*)d_in[5];
    const float* bn2 = (const float*)d_in[6];
    const float* Wm1 = (const float*)d_in[7];
    const float* bm1 = (const float*)d_in[8];
    const float* Wm2 = (const float*)d_in[9];
    const float* bm2 = (const float*)d_in[10];
    const float* Wr1 = (const float*)d_in[11];
    const float* br1 = (const float*)d_in[12];
    const float* wr2 = (const float*)d_in[13];
    const float* br2 = (const float*)d_in[14];
    float* out = (float*)d_out;
    float* ws  = (float*)d_ws;
    int*   bar = (int*)(ws + 1582336);   // 16 slots x 64 ints, past all buffers

    hipMemsetAsync(bar, 0, 16 * 64 * sizeof(int), stream);
    fused_k<<<NBLK, 256, 0, stream>>>(qf, sf, y, Wn1, bn1, Wn2, bn2,
                                      Wm1, bm1, Wm2, bm2, Wr1, br1, wr2, br2,
                                      out, ws, bar);
}